// Round 4
// baseline (131.737 us; speedup 1.0000x reference)
//
#include <hip/hip_runtime.h>
#include <stdint.h>

typedef unsigned long long u64;

// Problem constants (from reference file)
constexpr int B_ = 4;
constexpr int N_ = 160;
constexpr int T_ = 512;
constexpr int W_ = T_ / 64;   // 8 u64 words per 512-bit row

// ---------------------------------------------------------------------------
// Kernel 1: gather + bit-pack tag rows. grid = B*N blocks, 64 threads.
// Block 0 thread 0 also zeroes the done-counter for the last-block reduction.
// ---------------------------------------------------------------------------
__global__ __launch_bounds__(64) void pack_tags(const float* __restrict__ emb,
                                                const int* __restrict__ preds,
                                                u64* __restrict__ tags,
                                                int* __restrict__ counter) {
    int row  = blockIdx.x;            // b*N + r
    int lane = threadIdx.x;           // 0..63
    if (row == 0 && lane == 0) *counter = 0;
    const float* src = emb + (long long)preds[row] * T_;
#pragma unroll
    for (int w = 0; w < W_; ++w) {
        float v = src[w * 64 + lane];
        u64 m = __ballot(v != 0.0f);
        if (lane == 0) tags[(long long)row * W_ + w] = m;
    }
}

// ---------------------------------------------------------------------------
// Kernel 2 (fused pack_M + parallel prefix-OR scan + stats).
// grid = B blocks, 256 threads.
// ---------------------------------------------------------------------------
__global__ __launch_bounds__(256) void pack_scan(const float* __restrict__ Mf,
                                                 const u64* __restrict__ tags,
                                                 u64* __restrict__ Mp,
                                                 u64* __restrict__ P,
                                                 float* __restrict__ cU,
                                                 float* __restrict__ Mc) {
    __shared__ u64 S0[N_ * W_];
    __shared__ u64 S1[N_ * W_];
    __shared__ u64 Msh[W_];

    const int b    = blockIdx.x;
    const int tid  = threadIdx.x;
    const int lane = tid & 63;
    const int wv   = tid >> 6;        // wave id, 0..3

    for (int w = wv; w < W_; w += 4) {
        float v = Mf[(long long)b * T_ + w * 64 + lane];
        u64 m = __ballot(v != 0.0f);
        if (lane == 0) { Msh[w] = m; Mp[b * W_ + w] = m; }
    }
    for (int x = tid; x < N_ * W_; x += 256)
        S0[x] = tags[(long long)b * N_ * W_ + x];
    __syncthreads();

    u64* src = S0;
    u64* dst = S1;
    for (int d = 1; d < N_; d <<= 1) {
        for (int x = tid; x < N_ * W_; x += 256) {
            int r = x >> 3;           // W_ == 8
            u64 v = src[x];
            if (r >= d) v |= src[x - d * W_];
            dst[x] = v;
        }
        __syncthreads();
        u64* t = src; src = dst; dst = t;
    }

    for (int x = tid; x < N_ * W_; x += 256)
        P[(long long)b * N_ * W_ + x] = src[x];

    if (tid < N_) {
        int c = 0;
#pragma unroll
        for (int w = 0; w < W_; ++w)
            c += __popcll(Msh[w] & ~src[tid * W_ + w]);
        cU[b * N_ + tid] = (float)c;
    }
    if (tid == 0) {
        int c = 0;
#pragma unroll
        for (int w = 0; w < W_; ++w) c += __popcll(Msh[w]);
        Mc[b] = (float)(c + 1);
    }
}

// ---------------------------------------------------------------------------
// Kernel 3: main + fused finalize. grid = (N, B) over k, 192 threads.
// Block (k,b):
//   suffix-OR scan over rows [0,k): S[r] = OR tags[r..k-1]  (trimmed steps)
//   awL[i] = M & ~pre_i & ~S[i+1]   (built into the idle scan buffer)
//   sweep: thread = j (k<j<N), b_j in 16 VGPRs; loop i=0..k reading awL[i]
//          with a WAVE-UNIFORM LDS address (broadcast, conflict-free).
//   last finished block reduces all partials -> out (threadfence pattern).
// ---------------------------------------------------------------------------
__global__ __launch_bounds__(192) void lambda_main(const u64* __restrict__ tags,
                                                   const u64* __restrict__ Mp,
                                                   const u64* __restrict__ P,
                                                   const float* __restrict__ cU,
                                                   const float* __restrict__ Mc,
                                                   const float* __restrict__ scores,
                                                   double* __restrict__ partials,
                                                   int* __restrict__ counter,
                                                   float* __restrict__ out) {
    __shared__ u64 tagsL[N_ * W_];
    __shared__ u64 S0[N_ * W_];
    __shared__ u64 S1[N_ * W_];
    __shared__ u64 Msh[W_];
    __shared__ float scoresL[N_];
    __shared__ float redF[3];
    __shared__ int isLast;
    __shared__ double redD[3];

    const int k   = blockIdx.x;
    const int b   = blockIdx.y;
    const int tid = threadIdx.x;

    if (tid < W_) Msh[tid] = Mp[b * W_ + tid];
    for (int x = tid; x < N_; x += 192) scoresL[x] = scores[b * N_ + x];
    for (int x = tid; x < N_ * W_; x += 192)
        tagsL[x] = tags[(long long)b * N_ * W_ + x];
    __syncthreads();

    // ---- suffix OR scan over rows [0,k) ----
    const int ne = k * W_;
    u64* src = S0;
    u64* dst = S1;
    for (int x = tid; x < ne; x += 192) src[x] = tagsL[x];
    __syncthreads();
    for (int d = 1; d < k; d <<= 1) {       // k uniform -> barriers uniform
        for (int x = tid; x < ne; x += 192) {
            int r = x >> 3;
            u64 v = src[x];
            if (r + d < k) v |= src[x + d * W_];
            dst[x] = v;
        }
        __syncthreads();
        u64* t = src; src = dst; dst = t;
    }
    // src[r*W_+w] = OR of tags[r..k-1] for r < k

    // ---- build awL (into the idle buffer) for i in [0,k] ----
    u64* awL = dst;
    for (int x = tid; x < (k + 1) * W_; x += 192) {
        int i = x >> 3, w = x & 7;
        u64 pre;
        if (i == 1) pre = 0ull;
        else {
            int sr = (i == 0) ? (N_ - 2) : (i - 2);
            pre = P[((long long)b * N_ + sr) * W_ + w];
        }
        u64 sv = (i + 1 < k) ? src[(i + 1) * W_ + w] : 0ull;
        awL[x] = Msh[w] & ~pre & ~sv;
    }
    __syncthreads();

    // ---- sweep: thread = j, loop over i (awL read is wave-uniform) ----
    const int m = N_ - 1 - k;         // number of j values, <= 159 < 192
    float val = 0.0f;
    if (tid < m) {
        const int j = k + 1 + tid;
        u64 Bw[W_];
#pragma unroll
        for (int w = 0; w < W_; ++w) Bw[w] = Msh[w] & ~tagsL[j * W_ + w];
        const float sj  = scoresL[j];
        const float cUk = cU[b * N_ + k];
        float accLam = 0.0f, accC = 0.0f;
#pragma unroll 4
        for (int i = 0; i <= k; ++i) {
            int cc = 0;
#pragma unroll
            for (int w = 0; w < W_; ++w)
                cc += __popcll(awL[i * W_ + w] & Bw[w]);
            float lam = 1.0f / (1.0f + __expf(scoresL[i] - sj));
            accLam += lam;
            accC   += lam * (float)cc;
        }
        val = cUk * accLam - accC;
    }
    for (int off = 32; off >= 1; off >>= 1) val += __shfl_down(val, off, 64);
    if ((tid & 63) == 0) redF[tid >> 6] = val;
    __syncthreads();
    if (tid == 0) {
        float s = redF[0] + redF[1] + redF[2];
        float invlog = 1.0f / log2f((float)(k + 2));
        partials[b * N_ + k] = (double)(s * invlog) / (double)Mc[b];
        __threadfence();
        int done = atomicAdd(counter, 1);
        isLast = (done == N_ * B_ - 1) ? 1 : 0;
    }
    __syncthreads();

    // ---- last block: reduce all partials -> scalar out ----
    if (isLast) {
        __threadfence();              // acquire: see other blocks' partials
        double s = 0.0;
        for (int x = tid; x < B_ * N_; x += 192) s += partials[x];
        for (int off = 32; off >= 1; off >>= 1) s += __shfl_down(s, off, 64);
        if ((tid & 63) == 0) redD[tid >> 6] = s;
        __syncthreads();
        if (tid == 0) {
            double t = redD[0] + redD[1] + redD[2];
            out[0] = (float)(t / ((double)(N_ + 1) * (double)B_));
        }
    }
}

// ---------------------------------------------------------------------------
extern "C" void kernel_launch(void* const* d_in, const int* in_sizes, int n_in,
                              void* d_out, int out_size, void* d_ws, size_t ws_size,
                              hipStream_t stream) {
    const float* y_scores = (const float*)d_in[0];   // B*N f32
    const float* Mf       = (const float*)d_in[1];   // B*T f32
    const float* emb      = (const float*)d_in[2];   // NUM_API*T f32
    const int*   preds    = (const int*)d_in[3];     // B*N i32
    float* out = (float*)d_out;

    // workspace layout (all 8-byte aligned)
    u64* tags = (u64*)d_ws;                               // B*N*W
    u64* P    = tags + (size_t)B_ * N_ * W_;              // B*N*W
    u64* Mp   = P + (size_t)B_ * N_ * W_;                 // B*W
    double* partials = (double*)(Mp + B_ * W_);           // B*N
    float* cU = (float*)(partials + B_ * N_);             // B*N
    float* Mc = cU + B_ * N_;                             // B
    int* counter = (int*)(Mc + B_);                       // 1

    pack_tags<<<B_ * N_, 64, 0, stream>>>(emb, preds, tags, counter);
    pack_scan<<<B_, 256, 0, stream>>>(Mf, tags, Mp, P, cU, Mc);
    dim3 grid(N_, B_);
    lambda_main<<<grid, 192, 0, stream>>>(tags, Mp, P, cU, Mc, y_scores,
                                          partials, counter, out);
}